// Round 4
// 11182.471 us; speedup vs baseline: 1.3866x; 1.3866x over previous
//
#include <hip/hip_runtime.h>
#include <math.h>

// ---------------------------------------------------------------------------
// MinVQVAE forward on MI355X — Round 4 (= Round 2/3 resubmitted; two broker
// infra failures with no timing dict = container died before kernel compile).
//   Discrete path (encoder -> z_e -> score/argmax) must be BIT-IDENTICAL to
//   the verified-passing fp32 round: argmax rows with ~1e-5 score gaps flip
//   under any change of accumulation structure (round-1 lesson, absmax 0.10).
//   * encoder: fp32 VALU GEMM, identical per-output fmaf chains (k ascending),
//     but thread->output remapping (tx*4 / tx*4+64) to kill the 4-way LDS
//     bank conflict (3.35e8/dispatch) — mapping changes no bits.
//   * score_argmax: untouched.
//   * decoder: MFMA 2-way bf16-split GEMMs (no discrete decisions; logit
//     noise ~1e-5 << bf16-comparison floor 0.0039).
// ---------------------------------------------------------------------------

typedef __attribute__((ext_vector_type(8))) short  bf16x8;
typedef __attribute__((ext_vector_type(4))) float  f32x4;

__device__ __forceinline__ unsigned short bf16_rne(float f) {
    unsigned int u = __float_as_uint(f);
    u += 0x7FFFu + ((u >> 16) & 1u);
    return (unsigned short)(u >> 16);
}
__device__ __forceinline__ float bf16_tof(unsigned short h) {
    return __uint_as_float(((unsigned int)h) << 16);
}

__device__ __forceinline__ void gload16(const void* g, void* l) {
    __builtin_amdgcn_global_load_lds(
        (const __attribute__((address_space(1))) void*)g,
        (__attribute__((address_space(3))) void*)l, 16, 0, 0);
}

#define BM 128
#define BN 128
#define BK 16

// ----------------------- fp32 VALU GEMM (encoder) --------------------------
// Bit-exact vs the passing round: each output's chain is fmaf over k ascending
// (k0 blocks of 16, kk 0..15). Only the thread->output mapping changed
// (conflict-free LDS reads); per-element arithmetic identical.
// ACT: 0 = none, 1 = exact GELU (erf).
template<int ACT>
__global__ __launch_bounds__(256) void gemm_nt(
    const float* __restrict__ A, const float* __restrict__ Bw,
    const float* __restrict__ bias, float* __restrict__ C,
    int M, int N, int K)
{
    __shared__ float As[BK][BM + 4];
    __shared__ float Bs[BK][BN + 4];

    const int tid = threadIdx.x;
    const int tx = tid & 15;          // 16 col-groups
    const int ty = tid >> 4;          // 16 row-groups
    const int m0 = blockIdx.y * BM;
    const int n0 = blockIdx.x * BN;
    const int lr = tid >> 2;          // 0..63 (row within half-tile)
    const int lk = (tid & 3) << 2;    // 0,4,8,12 (k offset)

    float acc[8][8];
    #pragma unroll
    for (int i = 0; i < 8; ++i)
        #pragma unroll
        for (int j = 0; j < 8; ++j) acc[i][j] = 0.0f;

    const float* Ap = A + (size_t)(m0 + lr) * K + lk;
    const float* Bp = Bw + (size_t)(n0 + lr) * K + lk;
    const size_t strideR = (size_t)64 * K;

    for (int k0 = 0; k0 < K; k0 += BK) {
        float4 a0 = *(const float4*)(Ap + k0);
        float4 a1 = *(const float4*)(Ap + k0 + strideR);
        float4 b0 = *(const float4*)(Bp + k0);
        float4 b1 = *(const float4*)(Bp + k0 + strideR);
        __syncthreads();
        As[lk+0][lr]    = a0.x; As[lk+1][lr]    = a0.y; As[lk+2][lr]    = a0.z; As[lk+3][lr]    = a0.w;
        As[lk+0][lr+64] = a1.x; As[lk+1][lr+64] = a1.y; As[lk+2][lr+64] = a1.z; As[lk+3][lr+64] = a1.w;
        Bs[lk+0][lr]    = b0.x; Bs[lk+1][lr]    = b0.y; Bs[lk+2][lr]    = b0.z; Bs[lk+3][lr]    = b0.w;
        Bs[lk+0][lr+64] = b1.x; Bs[lk+1][lr+64] = b1.y; Bs[lk+2][lr+64] = b1.z; Bs[lk+3][lr+64] = b1.w;
        __syncthreads();
        #pragma unroll
        for (int kk = 0; kk < BK; ++kk) {
            float a_[8], b_[8];
            // conflict-free: 64 consecutive floats per wave group (2-way = free)
            *(float4*)&a_[0] = *(const float4*)&As[kk][ty * 4];
            *(float4*)&a_[4] = *(const float4*)&As[kk][ty * 4 + 64];
            *(float4*)&b_[0] = *(const float4*)&Bs[kk][tx * 4];
            *(float4*)&b_[4] = *(const float4*)&Bs[kk][tx * 4 + 64];
            #pragma unroll
            for (int i = 0; i < 8; ++i)
                #pragma unroll
                for (int j = 0; j < 8; ++j)
                    acc[i][j] = fmaf(a_[i], b_[j], acc[i][j]);
        }
    }

    float bv[8];
    *(float4*)&bv[0] = *(const float4*)&bias[n0 + tx * 4];
    *(float4*)&bv[4] = *(const float4*)&bias[n0 + 64 + tx * 4];

    #pragma unroll
    for (int i = 0; i < 8; ++i) {
        const int rbase = (i < 4) ? (ty * 4 + i) : (64 + ty * 4 + (i - 4));
        const size_t row = (size_t)(m0 + rbase);
        float out[8];
        #pragma unroll
        for (int j = 0; j < 8; ++j) {
            float v = acc[i][j] + bv[j];
            if (ACT == 1) v = 0.5f * v * (1.0f + erff(v * 0.70710678118654752440f));
            out[j] = v;
        }
        float* cp0 = C + row * N + n0 + tx * 4;
        float* cp1 = C + row * N + n0 + 64 + tx * 4;
        *(float4*)cp0 = *(const float4*)&out[0];
        *(float4*)cp1 = *(const float4*)&out[4];
    }
}

// --------------------------- split fp32 -> bf16 parts ----------------------
__global__ __launch_bounds__(256) void split_bf16_2(
    const float* __restrict__ in, unsigned short* __restrict__ o0,
    unsigned short* __restrict__ o1, int n4)
{
    int i = blockIdx.x * 256 + threadIdx.x;
    if (i >= n4) return;
    float4 v = ((const float4*)in)[i];
    ushort4 a, b;
    float* vp = (float*)&v;
    unsigned short* ap = (unsigned short*)&a;
    unsigned short* bp = (unsigned short*)&b;
    #pragma unroll
    for (int k = 0; k < 4; ++k) {
        float x = vp[k];
        unsigned short h0 = bf16_rne(x);
        float r = x - bf16_tof(h0);
        ap[k] = h0; bp[k] = bf16_rne(r);
    }
    ((ushort4*)o0)[i] = a;
    ((ushort4*)o1)[i] = b;
}

// --------------------------- split-bf16 MFMA GEMM (decoder) ----------------
// C = A * B^T + bias, A:[M][K] 2 parts, B:[N][K] 2 parts. 3 passes (ia+ib<2).
// ACT: 1 exact GELU(erf), 2 sigmoid (+ fused sum((x-pred)^2)).
// OUT: 0 fp32 (Cf), 2 two-part bf16 (C0,C1).
template<int ACT, int OUT>
__global__ __launch_bounds__(256) void gemm_split(
    const unsigned short* __restrict__ A0, const unsigned short* __restrict__ A1,
    const unsigned short* __restrict__ B0, const unsigned short* __restrict__ B1,
    const float* __restrict__ bias,
    float* __restrict__ Cf,
    unsigned short* __restrict__ C0, unsigned short* __restrict__ C1,
    int M, int N, int K,
    const float* __restrict__ Xref, float* __restrict__ sse_acc)
{
    __shared__ unsigned short As[128 * 64];   // 16 KiB, rows of 64 bf16 (128 B)
    __shared__ unsigned short Bs[128 * 64];   // 16 KiB
    __shared__ float red[4];

    const int tid  = threadIdx.x;
    const int lane = tid & 63;
    const int wid  = tid >> 6;
    const int wm   = wid >> 1;
    const int wn   = wid & 1;
    const int m0   = blockIdx.y * 128;
    const int n0   = blockIdx.x * 128;

    // staging: linear LDS dest (it*4096 + tid*16); XOR slot-swizzle applied on
    // the GLOBAL source so LDS[row][s] = global[row][s ^ ((row&7)<<4)].
    const int sr  = tid >> 3;
    const int scb = ((tid & 7) << 4) ^ ((sr & 7) << 4);

    const int l15  = lane & 15;
    const int xorr = (lane & 7) << 4;
    const int ksl0 = (((lane >> 4) << 4)     ) ^ xorr;
    const int ksl1 = (((lane >> 4) << 4) + 64) ^ xorr;

    f32x4 acc[4][4];
    const f32x4 fzero = {0.0f, 0.0f, 0.0f, 0.0f};
    #pragma unroll
    for (int i = 0; i < 4; ++i)
        #pragma unroll
        for (int j = 0; j < 4; ++j) acc[i][j] = fzero;

    #pragma unroll 1
    for (int ia = 0; ia < 2; ++ia) {
        #pragma unroll 1
        for (int ib = 0; ia + ib < 2; ++ib) {
            const unsigned short* Ap = (ia == 0) ? A0 : A1;
            const unsigned short* Bp = (ib == 0) ? B0 : B1;
            #pragma unroll 1
            for (int k0 = 0; k0 < K; k0 += 64) {
                __syncthreads();
                #pragma unroll
                for (int it = 0; it < 4; ++it) {
                    gload16((const char*)(Ap + (size_t)(m0 + it * 32 + sr) * K + k0) + scb,
                            (char*)As + it * 4096 + tid * 16);
                    gload16((const char*)(Bp + (size_t)(n0 + it * 32 + sr) * K + k0) + scb,
                            (char*)Bs + it * 4096 + tid * 16);
                }
                __syncthreads();
                #pragma unroll
                for (int kb = 0; kb < 2; ++kb) {
                    const int ks = kb ? ksl1 : ksl0;
                    bf16x8 av[4], bv[4];
                    #pragma unroll
                    for (int i = 0; i < 4; ++i) {
                        av[i] = *(const bf16x8*)((const char*)As + (wm * 64 + i * 16 + l15) * 128 + ks);
                        bv[i] = *(const bf16x8*)((const char*)Bs + (wn * 64 + i * 16 + l15) * 128 + ks);
                    }
                    #pragma unroll
                    for (int i = 0; i < 4; ++i)
                        #pragma unroll
                        for (int j = 0; j < 4; ++j)
                            acc[i][j] = __builtin_amdgcn_mfma_f32_16x16x32_bf16(
                                av[i], bv[j], acc[i][j], 0, 0, 0);
                }
            }
        }
    }

    float bj[4];
    #pragma unroll
    for (int j = 0; j < 4; ++j) bj[j] = bias[n0 + wn * 64 + j * 16 + l15];

    float sse_local = 0.0f;
    const int r4 = (lane >> 4) << 2;
    #pragma unroll
    for (int i = 0; i < 4; ++i) {
        #pragma unroll
        for (int v = 0; v < 4; ++v) {
            const size_t m = (size_t)(m0 + wm * 64 + i * 16 + r4 + v);
            #pragma unroll
            for (int j = 0; j < 4; ++j) {
                const size_t n = (size_t)(n0 + wn * 64 + j * 16 + l15);
                float val = acc[i][j][v] + bj[j];
                if (ACT == 1)      val = 0.5f * val * (1.0f + erff(val * 0.70710678118654752440f));
                else if (ACT == 2) val = 1.0f / (1.0f + expf(-val));
                const size_t off = m * (size_t)N + n;
                if (OUT == 0) {
                    Cf[off] = val;
                    if (ACT == 2) {
                        float d = Xref[off] - val;
                        sse_local = fmaf(d, d, sse_local);
                    }
                } else {
                    unsigned short h0 = bf16_rne(val);
                    float r = val - bf16_tof(h0);
                    C0[off] = h0; C1[off] = bf16_rne(r);
                }
            }
        }
    }

    if (ACT == 2) {
        #pragma unroll
        for (int off = 32; off > 0; off >>= 1) sse_local += __shfl_down(sse_local, off);
        if (lane == 0) red[wid] = sse_local;
        __syncthreads();
        if (tid == 0) atomicAdd(sse_acc, red[0] + red[1] + red[2] + red[3]);
    }
}

// ------------------- fp32 scoring + argmax (bit-identical) -----------------
__global__ __launch_bounds__(256) void score_argmax(
    const float* __restrict__ Z, const float* __restrict__ E,
    int* __restrict__ idx_out)
{
    __shared__ float As[BK][BM + 4];
    __shared__ float Bs[BK][BN + 4];
    __shared__ float rv[BM][17];
    __shared__ int   ri[BM][17];

    const int tid = threadIdx.x;
    const int tx = tid & 15;
    const int ty = tid >> 4;
    const int m0 = blockIdx.x * BM;
    const int lr = tid >> 2;
    const int lk = (tid & 3) << 2;

    const float* Ap = Z + (size_t)(m0 + lr) * 256 + lk;

    float best[8]; int besti[8];
    #pragma unroll
    for (int i = 0; i < 8; ++i) { best[i] = -3.4e38f; besti[i] = 0; }

    for (int c0 = 0; c0 < 1024; c0 += BN) {
        float acc[8][8];
        #pragma unroll
        for (int i = 0; i < 8; ++i)
            #pragma unroll
            for (int j = 0; j < 8; ++j) acc[i][j] = 0.0f;

        const float* Bp = E + (size_t)(c0 + lr) * 256 + lk;
        for (int k0 = 0; k0 < 256; k0 += BK) {
            float4 a0 = *(const float4*)(Ap + k0);
            float4 a1 = *(const float4*)(Ap + k0 + (size_t)64 * 256);
            float4 b0 = *(const float4*)(Bp + k0);
            float4 b1 = *(const float4*)(Bp + k0 + (size_t)64 * 256);
            __syncthreads();
            As[lk+0][lr]    = a0.x; As[lk+1][lr]    = a0.y; As[lk+2][lr]    = a0.z; As[lk+3][lr]    = a0.w;
            As[lk+0][lr+64] = a1.x; As[lk+1][lr+64] = a1.y; As[lk+2][lr+64] = a1.z; As[lk+3][lr+64] = a1.w;
            Bs[lk+0][lr]    = b0.x; Bs[lk+1][lr]    = b0.y; Bs[lk+2][lr]    = b0.z; Bs[lk+3][lr]    = b0.w;
            Bs[lk+0][lr+64] = b1.x; Bs[lk+1][lr+64] = b1.y; Bs[lk+2][lr+64] = b1.z; Bs[lk+3][lr+64] = b1.w;
            __syncthreads();
            #pragma unroll
            for (int kk = 0; kk < BK; ++kk) {
                float a_[8], b_[8];
                *(float4*)&a_[0] = *(const float4*)&As[kk][ty * 8];
                *(float4*)&a_[4] = *(const float4*)&As[kk][ty * 8 + 4];
                *(float4*)&b_[0] = *(const float4*)&Bs[kk][tx * 8];
                *(float4*)&b_[4] = *(const float4*)&Bs[kk][tx * 8 + 4];
                #pragma unroll
                for (int i = 0; i < 8; ++i)
                    #pragma unroll
                    for (int j = 0; j < 8; ++j)
                        acc[i][j] = fmaf(a_[i], b_[j], acc[i][j]);
            }
        }
        #pragma unroll
        for (int j = 0; j < 8; ++j) {
            const int col = c0 + tx * 8 + j;
            #pragma unroll
            for (int i = 0; i < 8; ++i) {
                if (acc[i][j] > best[i]) { best[i] = acc[i][j]; besti[i] = col; }
            }
        }
    }

    #pragma unroll
    for (int i = 0; i < 8; ++i) { rv[ty * 8 + i][tx] = best[i]; ri[ty * 8 + i][tx] = besti[i]; }
    __syncthreads();
    if (tid < BM) {
        float bvv = rv[tid][0]; int bii = ri[tid][0];
        #pragma unroll
        for (int t = 1; t < 16; ++t) {
            float v = rv[tid][t]; int ii = ri[tid][t];
            if (v > bvv || (v == bvv && ii < bii)) { bvv = v; bii = ii; }
        }
        idx_out[m0 + tid] = bii;
    }
}

// ------- z_q gather (bf16 parts) + one-hot scatter + sum((z_e-z_q)^2) ------
__global__ __launch_bounds__(256) void gather_zq(
    const float* __restrict__ Z, const float* __restrict__ E,
    const unsigned short* __restrict__ E0, const unsigned short* __restrict__ E1,
    const int* __restrict__ idx,
    unsigned short* __restrict__ Zq0, unsigned short* __restrict__ Zq1,
    float* __restrict__ onehot, float* __restrict__ acc)
{
    __shared__ float red[4];
    const size_t g = (size_t)blockIdx.x * 256 + threadIdx.x;
    const int q = (int)(g >> 8);
    const int d = (int)(g & 255);
    const int c = idx[q];
    const size_t eoff = (size_t)c * 256 + d;
    const float e = E[eoff];
    const float z = Z[g];
    Zq0[g] = E0[eoff];
    Zq1[g] = E1[eoff];
    if (d == 0) onehot[(size_t)q * 1024 + c] = 1.0f;
    float v = (z - e) * (z - e);
    #pragma unroll
    for (int off = 32; off > 0; off >>= 1) v += __shfl_down(v, off);
    if ((threadIdx.x & 63) == 0) red[threadIdx.x >> 6] = v;
    __syncthreads();
    if (threadIdx.x == 0) atomicAdd(acc + 1, red[0] + red[1] + red[2] + red[3]);
}

__global__ void finalize_loss(const float* __restrict__ acc, float* __restrict__ out)
{
    const float m1 = acc[0] * (1.0f / (4096.0f * 3072.0f));
    const float m2 = acc[1] * (1.0f / (4096.0f * 32.0f * 256.0f));
    out[0] = (m1 + 1.25f * m2) * (1.0f / 4096.0f);
}

// ---------------------------------------------------------------------------
extern "C" void kernel_launch(void* const* d_in, const int* in_sizes, int n_in,
                              void* d_out, int out_size, void* d_ws, size_t ws_size,
                              hipStream_t stream)
{
    const float* x   = (const float*)d_in[0];
    const float* E   = (const float*)d_in[1];
    const float* ew1 = (const float*)d_in[2];
    const float* eb1 = (const float*)d_in[3];
    const float* ew2 = (const float*)d_in[4];
    const float* eb2 = (const float*)d_in[5];
    const float* ew3 = (const float*)d_in[6];
    const float* eb3 = (const float*)d_in[7];
    const float* dw1 = (const float*)d_in[8];
    const float* db1 = (const float*)d_in[9];
    const float* dw2 = (const float*)d_in[10];
    const float* db2 = (const float*)d_in[11];
    const float* dw3 = (const float*)d_in[12];
    const float* db3 = (const float*)d_in[13];

    float* outf   = (float*)d_out;
    float* xpred  = outf;                                  // 4096*3072 f32
    float* onehot = outf + (size_t)4096 * 3072;            // 4096*32*1024 f32
    float* loss   = onehot + (size_t)4096 * 32 * 1024;     // 1 f32

    // encoder-phase scratch in the one-hot region (dead until its memset)
    char* oh = (char*)onehot;
    float* H1 = (float*)(oh);                              // 4096*4096 f32
    float* H2 = (float*)(oh + 67108864);                   // 4096*4096 f32 (ends 128MB < 537MB)

    // persistent workspace (~385 MiB; round-0 proved more than this is fine)
    char* ws = (char*)d_ws;
    float*          ZE  = (float*)(ws);                    // 4096*8192 f32 (dead after gather_zq)
    unsigned short* V0  = (unsigned short*)(ws);           // overlays ZE (decoder weights)
    unsigned short* V1  = (unsigned short*)(ws + 67108864);
    unsigned short* ZQ0 = (unsigned short*)(ws + 134217728);
    unsigned short* ZQ1 = (unsigned short*)(ws + 201326592);
    unsigned short* G10 = (unsigned short*)(ws + 268435456);
    unsigned short* G11 = (unsigned short*)(ws + 301989888);
    unsigned short* G20 = (unsigned short*)(ws + 335544320);
    unsigned short* G21 = (unsigned short*)(ws + 369098752);
    unsigned short* E0  = (unsigned short*)(ws + 402653184);
    unsigned short* E1  = (unsigned short*)(ws + 403177472);
    int*   IDX = (int*)  (ws + 403701760);
    float* ACC = (float*)(ws + 404226048);

    dim3 blk(256);

    // ---- encoder: fp32 VALU, bit-identical chains to the passing round ----
    gemm_nt<1><<<dim3(32, 32), blk, 0, stream>>>(x,  ew1, eb1, H1, 4096, 4096, 3072);
    gemm_nt<1><<<dim3(32, 32), blk, 0, stream>>>(H1, ew2, eb2, H2, 4096, 4096, 4096);
    gemm_nt<0><<<dim3(64, 32), blk, 0, stream>>>(H2, ew3, eb3, ZE, 4096, 8192, 4096);

    // ---- scoring + argmax (bit-identical) ----
    score_argmax<<<dim3(1024), blk, 0, stream>>>(ZE, E, IDX);

    // H1/H2 dead -> clear outputs
    hipMemsetAsync(ACC, 0, 2 * sizeof(float), stream);
    hipMemsetAsync(onehot, 0, (size_t)4096 * 32 * 1024 * sizeof(float), stream);

    split_bf16_2<<<256, blk, 0, stream>>>(E, E0, E1, 65536);
    gather_zq<<<dim3(131072), blk, 0, stream>>>(ZE, E, E0, E1, IDX, ZQ0, ZQ1, onehot, ACC);

    // ---- decoder: MFMA 2-way split (ZE dead; V overlays it) ----
    split_bf16_2<<<32768, blk, 0, stream>>>(dw1, V0, V1, 8388608);
    gemm_split<1,2><<<dim3(32, 32), blk, 0, stream>>>(ZQ0, ZQ1, V0, V1, db1,
        nullptr, G10, G11, 4096, 4096, 8192, nullptr, nullptr);
    split_bf16_2<<<16384, blk, 0, stream>>>(dw2, V0, V1, 4194304);
    gemm_split<1,2><<<dim3(32, 32), blk, 0, stream>>>(G10, G11, V0, V1, db2,
        nullptr, G20, G21, 4096, 4096, 4096, nullptr, nullptr);
    split_bf16_2<<<12288, blk, 0, stream>>>(dw3, V0, V1, 3145728);
    gemm_split<2,0><<<dim3(24, 32), blk, 0, stream>>>(G20, G21, V0, V1, db3,
        xpred, nullptr, nullptr, 4096, 3072, 4096, x, ACC);

    finalize_loss<<<1, 1, 0, stream>>>(ACC, loss);
}

// Round 5
// 10785.757 us; speedup vs baseline: 1.4376x; 1.0368x over previous
//
#include <hip/hip_runtime.h>
#include <math.h>

// ---------------------------------------------------------------------------
// MinVQVAE forward on MI355X — Round 5.
//   Discrete path (encoder -> z_e -> score/argmax) stays BIT-IDENTICAL to the
//   verified-passing fp32 rounds (argmax flips at ~1e-5 score gaps; z_q is an
//   exact gather so decoder precision only needs the 0.02 threshold).
//   * encoder gemm_nt: BK 16->32 (half the barriers) + launch_bounds(256,2)
//     (VGPR headroom for the 64 accumulators). Per-output fmaf chain still
//     k-ascending => bits identical.
//   * decoder gemm_split: FUSED 3-pass — stage A0,A1,B0,B1 tiles together,
//     3 MFMA products per staging phase (3x MFMA density vs round 4).
//   * score_argmax / gather / loss: untouched.
// ---------------------------------------------------------------------------

typedef __attribute__((ext_vector_type(8))) short  bf16x8;
typedef __attribute__((ext_vector_type(4))) float  f32x4;

__device__ __forceinline__ unsigned short bf16_rne(float f) {
    unsigned int u = __float_as_uint(f);
    u += 0x7FFFu + ((u >> 16) & 1u);
    return (unsigned short)(u >> 16);
}
__device__ __forceinline__ float bf16_tof(unsigned short h) {
    return __uint_as_float(((unsigned int)h) << 16);
}

__device__ __forceinline__ void gload16(const void* g, void* l) {
    __builtin_amdgcn_global_load_lds(
        (const __attribute__((address_space(1))) void*)g,
        (__attribute__((address_space(3))) void*)l, 16, 0, 0);
}

#define BM 128
#define BN 128
#define BK 16
#define BK2 32

// ----------------------- fp32 VALU GEMM (encoder) --------------------------
// Bit-exact vs the passing rounds: each output's chain is fmaf over k
// ascending. BK2=32 halves barrier count; staging order is arithmetic-neutral.
// ACT: 0 = none, 1 = exact GELU (erf).
template<int ACT>
__global__ __launch_bounds__(256, 2) void gemm_nt(
    const float* __restrict__ A, const float* __restrict__ Bw,
    const float* __restrict__ bias, float* __restrict__ C,
    int M, int N, int K)
{
    __shared__ float As[BK2][BM + 4];
    __shared__ float Bs[BK2][BN + 4];

    const int tid = threadIdx.x;
    const int tx = tid & 15;          // 16 col-groups
    const int ty = tid >> 4;          // 16 row-groups
    const int m0 = blockIdx.y * BM;
    const int n0 = blockIdx.x * BN;
    const int lr = tid >> 2;          // 0..63 (row within half-tile)
    const int lk = (tid & 3) << 2;    // 0,4,8,12 (k offset)

    float acc[8][8];
    #pragma unroll
    for (int i = 0; i < 8; ++i)
        #pragma unroll
        for (int j = 0; j < 8; ++j) acc[i][j] = 0.0f;

    const float* Ap = A + (size_t)(m0 + lr) * K + lk;
    const float* Bp = Bw + (size_t)(n0 + lr) * K + lk;
    const size_t strideR = (size_t)64 * K;

    for (int k0 = 0; k0 < K; k0 += BK2) {
        float4 a00 = *(const float4*)(Ap + k0);
        float4 a01 = *(const float4*)(Ap + k0 + 16);
        float4 a10 = *(const float4*)(Ap + k0 + strideR);
        float4 a11 = *(const float4*)(Ap + k0 + strideR + 16);
        float4 b00 = *(const float4*)(Bp + k0);
        float4 b01 = *(const float4*)(Bp + k0 + 16);
        float4 b10 = *(const float4*)(Bp + k0 + strideR);
        float4 b11 = *(const float4*)(Bp + k0 + strideR + 16);
        __syncthreads();
        As[lk+0][lr]     = a00.x; As[lk+1][lr]     = a00.y; As[lk+2][lr]     = a00.z; As[lk+3][lr]     = a00.w;
        As[lk+16][lr]    = a01.x; As[lk+17][lr]    = a01.y; As[lk+18][lr]    = a01.z; As[lk+19][lr]    = a01.w;
        As[lk+0][lr+64]  = a10.x; As[lk+1][lr+64]  = a10.y; As[lk+2][lr+64]  = a10.z; As[lk+3][lr+64]  = a10.w;
        As[lk+16][lr+64] = a11.x; As[lk+17][lr+64] = a11.y; As[lk+18][lr+64] = a11.z; As[lk+19][lr+64] = a11.w;
        Bs[lk+0][lr]     = b00.x; Bs[lk+1][lr]     = b00.y; Bs[lk+2][lr]     = b00.z; Bs[lk+3][lr]     = b00.w;
        Bs[lk+16][lr]    = b01.x; Bs[lk+17][lr]    = b01.y; Bs[lk+18][lr]    = b01.z; Bs[lk+19][lr]    = b01.w;
        Bs[lk+0][lr+64]  = b10.x; Bs[lk+1][lr+64]  = b10.y; Bs[lk+2][lr+64]  = b10.z; Bs[lk+3][lr+64]  = b10.w;
        Bs[lk+16][lr+64] = b11.x; Bs[lk+17][lr+64] = b11.y; Bs[lk+18][lr+64] = b11.z; Bs[lk+19][lr+64] = b11.w;
        __syncthreads();
        #pragma unroll
        for (int kk = 0; kk < BK2; ++kk) {
            float a_[8], b_[8];
            // conflict-free: broadcast / 64-consecutive-float groups
            *(float4*)&a_[0] = *(const float4*)&As[kk][ty * 4];
            *(float4*)&a_[4] = *(const float4*)&As[kk][ty * 4 + 64];
            *(float4*)&b_[0] = *(const float4*)&Bs[kk][tx * 4];
            *(float4*)&b_[4] = *(const float4*)&Bs[kk][tx * 4 + 64];
            #pragma unroll
            for (int i = 0; i < 8; ++i)
                #pragma unroll
                for (int j = 0; j < 8; ++j)
                    acc[i][j] = fmaf(a_[i], b_[j], acc[i][j]);
        }
    }

    float bv[8];
    *(float4*)&bv[0] = *(const float4*)&bias[n0 + tx * 4];
    *(float4*)&bv[4] = *(const float4*)&bias[n0 + 64 + tx * 4];

    #pragma unroll
    for (int i = 0; i < 8; ++i) {
        const int rbase = (i < 4) ? (ty * 4 + i) : (64 + ty * 4 + (i - 4));
        const size_t row = (size_t)(m0 + rbase);
        float out[8];
        #pragma unroll
        for (int j = 0; j < 8; ++j) {
            float v = acc[i][j] + bv[j];
            if (ACT == 1) v = 0.5f * v * (1.0f + erff(v * 0.70710678118654752440f));
            out[j] = v;
        }
        float* cp0 = C + row * N + n0 + tx * 4;
        float* cp1 = C + row * N + n0 + 64 + tx * 4;
        *(float4*)cp0 = *(const float4*)&out[0];
        *(float4*)cp1 = *(const float4*)&out[4];
    }
}

// --------------------------- split fp32 -> bf16 parts ----------------------
__global__ __launch_bounds__(256) void split_bf16_2(
    const float* __restrict__ in, unsigned short* __restrict__ o0,
    unsigned short* __restrict__ o1, int n4)
{
    int i = blockIdx.x * 256 + threadIdx.x;
    if (i >= n4) return;
    float4 v = ((const float4*)in)[i];
    ushort4 a, b;
    float* vp = (float*)&v;
    unsigned short* ap = (unsigned short*)&a;
    unsigned short* bp = (unsigned short*)&b;
    #pragma unroll
    for (int k = 0; k < 4; ++k) {
        float x = vp[k];
        unsigned short h0 = bf16_rne(x);
        float r = x - bf16_tof(h0);
        ap[k] = h0; bp[k] = bf16_rne(r);
    }
    ((ushort4*)o0)[i] = a;
    ((ushort4*)o1)[i] = b;
}

// ------------------- fused split-bf16 MFMA GEMM (decoder) ------------------
// C = A * B^T + bias with A ~ A0+A1, B ~ B0+B1 (2-way bf16 splits).
// FUSED: one K-loop stages A0,A1,B0,B1 tiles together and issues all three
// pass-products (a0b0 + a0b1 + a1b0) per staging phase — 3x MFMA per staged
// byte vs sequential passes. acc-order change is harmless (decoder only).
// ACT: 1 exact GELU(erf), 2 sigmoid (+ fused sum((x-pred)^2)).
// OUT: 0 fp32 (Cf), 2 two-part bf16 (C0,C1).
template<int ACT, int OUT>
__global__ __launch_bounds__(256, 2) void gemm_split(
    const unsigned short* __restrict__ A0, const unsigned short* __restrict__ A1,
    const unsigned short* __restrict__ B0, const unsigned short* __restrict__ B1,
    const float* __restrict__ bias,
    float* __restrict__ Cf,
    unsigned short* __restrict__ C0, unsigned short* __restrict__ C1,
    int M, int N, int K,
    const float* __restrict__ Xref, float* __restrict__ sse_acc)
{
    __shared__ unsigned short As0[128 * 64];  // 16 KiB each, rows of 64 bf16
    __shared__ unsigned short As1[128 * 64];
    __shared__ unsigned short Bs0[128 * 64];
    __shared__ unsigned short Bs1[128 * 64];
    __shared__ float red[4];

    const int tid  = threadIdx.x;
    const int lane = tid & 63;
    const int wid  = tid >> 6;
    const int wm   = wid >> 1;
    const int wn   = wid & 1;
    const int m0   = blockIdx.y * 128;
    const int n0   = blockIdx.x * 128;

    // staging: linear LDS dest (it*4096 + tid*16); XOR slot-swizzle applied on
    // the GLOBAL source so LDS[row][s] = global[row][s ^ ((row&7)<<4)].
    const int sr  = tid >> 3;
    const int scb = ((tid & 7) << 4) ^ ((sr & 7) << 4);

    const int l15  = lane & 15;
    const int xorr = (lane & 7) << 4;
    const int ksl0 = (((lane >> 4) << 4)     ) ^ xorr;
    const int ksl1 = (((lane >> 4) << 4) + 64) ^ xorr;

    f32x4 acc[4][4];
    const f32x4 fzero = {0.0f, 0.0f, 0.0f, 0.0f};
    #pragma unroll
    for (int i = 0; i < 4; ++i)
        #pragma unroll
        for (int j = 0; j < 4; ++j) acc[i][j] = fzero;

    #pragma unroll 1
    for (int k0 = 0; k0 < K; k0 += 64) {
        __syncthreads();                       // previous tile fully read
        #pragma unroll
        for (int it = 0; it < 4; ++it) {
            const size_t go = (size_t)(m0 + it * 32 + sr) * K + k0;
            const size_t ho = (size_t)(n0 + it * 32 + sr) * K + k0;
            const int lo = it * 4096 + tid * 16;
            gload16((const char*)(A0 + go) + scb, (char*)As0 + lo);
            gload16((const char*)(A1 + go) + scb, (char*)As1 + lo);
            gload16((const char*)(B0 + ho) + scb, (char*)Bs0 + lo);
            gload16((const char*)(B1 + ho) + scb, (char*)Bs1 + lo);
        }
        __syncthreads();                       // staging complete
        #pragma unroll
        for (int kb = 0; kb < 2; ++kb) {
            const int ks = kb ? ksl1 : ksl0;
            bf16x8 av0[4], av1[4], bv0[4], bv1[4];
            #pragma unroll
            for (int i = 0; i < 4; ++i) {
                const int ra = (wm * 64 + i * 16 + l15) * 128 + ks;
                const int rb = (wn * 64 + i * 16 + l15) * 128 + ks;
                av0[i] = *(const bf16x8*)((const char*)As0 + ra);
                av1[i] = *(const bf16x8*)((const char*)As1 + ra);
                bv0[i] = *(const bf16x8*)((const char*)Bs0 + rb);
                bv1[i] = *(const bf16x8*)((const char*)Bs1 + rb);
            }
            #pragma unroll
            for (int i = 0; i < 4; ++i)
                #pragma unroll
                for (int j = 0; j < 4; ++j) {
                    acc[i][j] = __builtin_amdgcn_mfma_f32_16x16x32_bf16(av0[i], bv0[j], acc[i][j], 0, 0, 0);
                    acc[i][j] = __builtin_amdgcn_mfma_f32_16x16x32_bf16(av0[i], bv1[j], acc[i][j], 0, 0, 0);
                    acc[i][j] = __builtin_amdgcn_mfma_f32_16x16x32_bf16(av1[i], bv0[j], acc[i][j], 0, 0, 0);
                }
        }
    }

    float bj[4];
    #pragma unroll
    for (int j = 0; j < 4; ++j) bj[j] = bias[n0 + wn * 64 + j * 16 + l15];

    float sse_local = 0.0f;
    const int r4 = (lane >> 4) << 2;
    #pragma unroll
    for (int i = 0; i < 4; ++i) {
        #pragma unroll
        for (int v = 0; v < 4; ++v) {
            const size_t m = (size_t)(m0 + wm * 64 + i * 16 + r4 + v);
            #pragma unroll
            for (int j = 0; j < 4; ++j) {
                const size_t n = (size_t)(n0 + wn * 64 + j * 16 + l15);
                float val = acc[i][j][v] + bj[j];
                if (ACT == 1)      val = 0.5f * val * (1.0f + erff(val * 0.70710678118654752440f));
                else if (ACT == 2) val = 1.0f / (1.0f + expf(-val));
                const size_t off = m * (size_t)N + n;
                if (OUT == 0) {
                    Cf[off] = val;
                    if (ACT == 2) {
                        float d = Xref[off] - val;
                        sse_local = fmaf(d, d, sse_local);
                    }
                } else {
                    unsigned short h0 = bf16_rne(val);
                    float r = val - bf16_tof(h0);
                    C0[off] = h0; C1[off] = bf16_rne(r);
                }
            }
        }
    }

    if (ACT == 2) {
        #pragma unroll
        for (int off = 32; off > 0; off >>= 1) sse_local += __shfl_down(sse_local, off);
        if (lane == 0) red[wid] = sse_local;
        __syncthreads();
        if (tid == 0) atomicAdd(sse_acc, red[0] + red[1] + red[2] + red[3]);
    }
}

// ------------------- fp32 scoring + argmax (bit-identical) -----------------
__global__ __launch_bounds__(256) void score_argmax(
    const float* __restrict__ Z, const float* __restrict__ E,
    int* __restrict__ idx_out)
{
    __shared__ float As[BK][BM + 4];
    __shared__ float Bs[BK][BN + 4];
    __shared__ float rv[BM][17];
    __shared__ int   ri[BM][17];

    const int tid = threadIdx.x;
    const int tx = tid & 15;
    const int ty = tid >> 4;
    const int m0 = blockIdx.x * BM;
    const int lr = tid >> 2;
    const int lk = (tid & 3) << 2;

    const float* Ap = Z + (size_t)(m0 + lr) * 256 + lk;

    float best[8]; int besti[8];
    #pragma unroll
    for (int i = 0; i < 8; ++i) { best[i] = -3.4e38f; besti[i] = 0; }

    for (int c0 = 0; c0 < 1024; c0 += BN) {
        float acc[8][8];
        #pragma unroll
        for (int i = 0; i < 8; ++i)
            #pragma unroll
            for (int j = 0; j < 8; ++j) acc[i][j] = 0.0f;

        const float* Bp = E + (size_t)(c0 + lr) * 256 + lk;
        for (int k0 = 0; k0 < 256; k0 += BK) {
            float4 a0 = *(const float4*)(Ap + k0);
            float4 a1 = *(const float4*)(Ap + k0 + (size_t)64 * 256);
            float4 b0 = *(const float4*)(Bp + k0);
            float4 b1 = *(const float4*)(Bp + k0 + (size_t)64 * 256);
            __syncthreads();
            As[lk+0][lr]    = a0.x; As[lk+1][lr]    = a0.y; As[lk+2][lr]    = a0.z; As[lk+3][lr]    = a0.w;
            As[lk+0][lr+64] = a1.x; As[lk+1][lr+64] = a1.y; As[lk+2][lr+64] = a1.z; As[lk+3][lr+64] = a1.w;
            Bs[lk+0][lr]    = b0.x; Bs[lk+1][lr]    = b0.y; Bs[lk+2][lr]    = b0.z; Bs[lk+3][lr]    = b0.w;
            Bs[lk+0][lr+64] = b1.x; Bs[lk+1][lr+64] = b1.y; Bs[lk+2][lr+64] = b1.z; Bs[lk+3][lr+64] = b1.w;
            __syncthreads();
            #pragma unroll
            for (int kk = 0; kk < BK; ++kk) {
                float a_[8], b_[8];
                *(float4*)&a_[0] = *(const float4*)&As[kk][ty * 8];
                *(float4*)&a_[4] = *(const float4*)&As[kk][ty * 8 + 4];
                *(float4*)&b_[0] = *(const float4*)&Bs[kk][tx * 8];
                *(float4*)&b_[4] = *(const float4*)&Bs[kk][tx * 8 + 4];
                #pragma unroll
                for (int i = 0; i < 8; ++i)
                    #pragma unroll
                    for (int j = 0; j < 8; ++j)
                        acc[i][j] = fmaf(a_[i], b_[j], acc[i][j]);
            }
        }
        #pragma unroll
        for (int j = 0; j < 8; ++j) {
            const int col = c0 + tx * 8 + j;
            #pragma unroll
            for (int i = 0; i < 8; ++i) {
                if (acc[i][j] > best[i]) { best[i] = acc[i][j]; besti[i] = col; }
            }
        }
    }

    #pragma unroll
    for (int i = 0; i < 8; ++i) { rv[ty * 8 + i][tx] = best[i]; ri[ty * 8 + i][tx] = besti[i]; }
    __syncthreads();
    if (tid < BM) {
        float bvv = rv[tid][0]; int bii = ri[tid][0];
        #pragma unroll
        for (int t = 1; t < 16; ++t) {
            float v = rv[tid][t]; int ii = ri[tid][t];
            if (v > bvv || (v == bvv && ii < bii)) { bvv = v; bii = ii; }
        }
        idx_out[m0 + tid] = bii;
    }
}

// ------- z_q gather (bf16 parts) + one-hot scatter + sum((z_e-z_q)^2) ------
__global__ __launch_bounds__(256) void gather_zq(
    const float* __restrict__ Z, const float* __restrict__ E,
    const unsigned short* __restrict__ E0, const unsigned short* __restrict__ E1,
    const int* __restrict__ idx,
    unsigned short* __restrict__ Zq0, unsigned short* __restrict__ Zq1,
    float* __restrict__ onehot, float* __restrict__ acc)
{
    __shared__ float red[4];
    const size_t g = (size_t)blockIdx.x * 256 + threadIdx.x;
    const int q = (int)(g >> 8);
    const int d = (int)(g & 255);
    const int c = idx[q];
    const size_t eoff = (size_t)c * 256 + d;
    const float e = E[eoff];
    const float z = Z[g];
    Zq0[g] = E0[eoff];
    Zq1[g] = E1[eoff];
    if (d == 0) onehot[(size_t)q * 1024 + c] = 1.0f;
    float v = (z - e) * (z - e);
    #pragma unroll
    for (int off = 32; off > 0; off >>= 1) v += __shfl_down(v, off);
    if ((threadIdx.x & 63) == 0) red[threadIdx.x >> 6] = v;
    __syncthreads();
    if (threadIdx.x == 0) atomicAdd(acc + 1, red[0] + red[1] + red[2] + red[3]);
}

__global__ void finalize_loss(const float* __restrict__ acc, float* __restrict__ out)
{
    const float m1 = acc[0] * (1.0f / (4096.0f * 3072.0f));
    const float m2 = acc[1] * (1.0f / (4096.0f * 32.0f * 256.0f));
    out[0] = (m1 + 1.25f * m2) * (1.0f / 4096.0f);
}

// ---------------------------------------------------------------------------
extern "C" void kernel_launch(void* const* d_in, const int* in_sizes, int n_in,
                              void* d_out, int out_size, void* d_ws, size_t ws_size,
                              hipStream_t stream)
{
    const float* x   = (const float*)d_in[0];
    const float* E   = (const float*)d_in[1];
    const float* ew1 = (const float*)d_in[2];
    const float* eb1 = (const float*)d_in[3];
    const float* ew2 = (const float*)d_in[4];
    const float* eb2 = (const float*)d_in[5];
    const float* ew3 = (const float*)d_in[6];
    const float* eb3 = (const float*)d_in[7];
    const float* dw1 = (const float*)d_in[8];
    const float* db1 = (const float*)d_in[9];
    const float* dw2 = (const float*)d_in[10];
    const float* db2 = (const float*)d_in[11];
    const float* dw3 = (const float*)d_in[12];
    const float* db3 = (const float*)d_in[13];

    float* outf   = (float*)d_out;
    float* xpred  = outf;                                  // 4096*3072 f32
    float* onehot = outf + (size_t)4096 * 3072;            // 4096*32*1024 f32
    float* loss   = onehot + (size_t)4096 * 32 * 1024;     // 1 f32

    // encoder-phase scratch in the one-hot region (dead until its memset)
    char* oh = (char*)onehot;
    float* H1 = (float*)(oh);                              // 4096*4096 f32
    float* H2 = (float*)(oh + 67108864);                   // 4096*4096 f32 (ends 128MB < 537MB)

    // persistent workspace (~385 MiB)
    char* ws = (char*)d_ws;
    float*          ZE  = (float*)(ws);                    // 4096*8192 f32 (dead after gather_zq)
    unsigned short* V0  = (unsigned short*)(ws);           // overlays ZE (decoder weights)
    unsigned short* V1  = (unsigned short*)(ws + 67108864);
    unsigned short* ZQ0 = (unsigned short*)(ws + 134217728);
    unsigned short* ZQ1 = (unsigned short*)(ws + 201326592);
    unsigned short* G10 = (unsigned short*)(ws + 268435456);
    unsigned short* G11 = (unsigned short*)(ws + 301989888);
    unsigned short* G20 = (unsigned short*)(ws + 335544320);
    unsigned short* G21 = (unsigned short*)(ws + 369098752);
    unsigned short* E0  = (unsigned short*)(ws + 402653184);
    unsigned short* E1  = (unsigned short*)(ws + 403177472);
    int*   IDX = (int*)  (ws + 403701760);
    float* ACC = (float*)(ws + 404226048);

    dim3 blk(256);

    // ---- encoder: fp32 VALU, bit-identical chains to the passing rounds ----
    gemm_nt<1><<<dim3(32, 32), blk, 0, stream>>>(x,  ew1, eb1, H1, 4096, 4096, 3072);
    gemm_nt<1><<<dim3(32, 32), blk, 0, stream>>>(H1, ew2, eb2, H2, 4096, 4096, 4096);
    gemm_nt<0><<<dim3(64, 32), blk, 0, stream>>>(H2, ew3, eb3, ZE, 4096, 8192, 4096);

    // ---- scoring + argmax (bit-identical) ----
    score_argmax<<<dim3(1024), blk, 0, stream>>>(ZE, E, IDX);

    // H1/H2 dead -> clear outputs
    hipMemsetAsync(ACC, 0, 2 * sizeof(float), stream);
    hipMemsetAsync(onehot, 0, (size_t)4096 * 32 * 1024 * sizeof(float), stream);

    split_bf16_2<<<256, blk, 0, stream>>>(E, E0, E1, 65536);
    gather_zq<<<dim3(131072), blk, 0, stream>>>(ZE, E, E0, E1, IDX, ZQ0, ZQ1, onehot, ACC);

    // ---- decoder: fused MFMA 2-way split (ZE dead; V overlays it) ----
    split_bf16_2<<<32768, blk, 0, stream>>>(dw1, V0, V1, 8388608);
    gemm_split<1,2><<<dim3(32, 32), blk, 0, stream>>>(ZQ0, ZQ1, V0, V1, db1,
        nullptr, G10, G11, 4096, 4096, 8192, nullptr, nullptr);
    split_bf16_2<<<16384, blk, 0, stream>>>(dw2, V0, V1, 4194304);
    gemm_split<1,2><<<dim3(32, 32), blk, 0, stream>>>(G10, G11, V0, V1, db2,
        nullptr, G20, G21, 4096, 4096, 4096, nullptr, nullptr);
    split_bf16_2<<<12288, blk, 0, stream>>>(dw3, V0, V1, 3145728);
    gemm_split<2,0><<<dim3(24, 32), blk, 0, stream>>>(G20, G21, V0, V1, db3,
        xpred, nullptr, nullptr, 4096, 3072, 4096, x, ACC);

    finalize_loss<<<1, 1, 0, stream>>>(ACC, loss);
}